// Round 5
// baseline (184.913 us; speedup 1.0000x reference)
//
#include <hip/hip_runtime.h>
#include <stdint.h>

#define SEQ 2048

typedef __attribute__((ext_vector_type(8))) short bf16x8;
typedef __attribute__((ext_vector_type(4))) float f32x4;

typedef const __attribute__((address_space(1))) unsigned int GVT;
typedef __attribute__((address_space(3))) unsigned int LVT;

static __device__ __forceinline__ unsigned short f2bf(float f) {
  unsigned u = __builtin_bit_cast(unsigned, f);
  u += 0x7fffu + ((u >> 16) & 1u);
  return (unsigned short)(u >> 16);
}

static __device__ __forceinline__ unsigned pk_bf16(float lo, float hi) {
  unsigned r;
  asm("v_cvt_pk_bf16_f32 %0, %1, %2" : "=v"(r) : "v"(lo), "v"(hi));
  return r;
}

// one kernel converts x, w_qkv, w_proj (saves 2 launch overheads)
__global__ __launch_bounds__(256) void cvt3_kernel(
    const float* __restrict__ s0, unsigned short* __restrict__ d0, int n0,
    const float* __restrict__ s1, unsigned short* __restrict__ d1, int n1,
    const float* __restrict__ s2, unsigned short* __restrict__ d2, int n2) {
  int i = blockIdx.x * 256 + threadIdx.x;
  const int stride = gridDim.x * 256;
  const int total = n0 + n1 + n2;
  for (; i < total; i += stride) {
    const float* s;
    unsigned short* d;
    int k;
    if (i < n0) { s = s0; d = d0; k = i; }
    else if (i < n0 + n1) { s = s1; d = d1; k = i - n0; }
    else { s = s2; d = d2; k = i - n0 - n1; }
    float4 v = reinterpret_cast<const float4*>(s)[k];
    ushort4 o;
    o.x = f2bf(v.x); o.y = f2bf(v.y); o.z = f2bf(v.z); o.w = f2bf(v.w);
    reinterpret_cast<ushort4*>(d)[k] = o;
  }
}

// ---------------- QKV GEMM: C[4096][3072] = Xbf @ Wqkv^T, scatter to q/k/vt ----------
// q: [32][2048][64] (pre-scaled by SCALE*log2e); k: [32][2048][64]; vt: [32][64][2048]
__global__ __launch_bounds__(256, 2) void gemm_qkv_kernel(
    const unsigned short* __restrict__ A,    // [4096][1024] bf16
    const unsigned short* __restrict__ Bt,   // [3072][1024] bf16
    const float* __restrict__ bias,          // [3072]
    unsigned short* __restrict__ qb,
    unsigned short* __restrict__ kbuf,
    unsigned short* __restrict__ vtbuf) {
  __shared__ __align__(16) unsigned short As[2][128 * 32];
  __shared__ __align__(16) unsigned short Bs[2][128 * 32];
  const int tid = threadIdx.x;
  const int lane = tid & 63;
  const int wid = tid >> 6;
  const int wr = wid >> 1, wc = wid & 1;
  // XCD-bijective swizzle: 768 blocks, 768/8 = 96 per XCD (4 bm-rows each)
  const int lin = blockIdx.y * 24 + blockIdx.x;
  const int wg = (lin & 7) * 96 + (lin >> 3);
  const int bm = wg / 24, bn = wg % 24;
  const int lr = lane & 15, hg = lane >> 4;

  f32x4 acc[4][4] = {};

  const int r0 = tid >> 2;                 // staging row
  const int c0 = (tid & 3) * 8;            // staging col (elements)

  auto STAGE = [&](int b, int kt) {
    const unsigned short* ga0 = A + (size_t)(bm * 128 + r0) * 1024 + kt * 32 + c0;
    const unsigned short* ga1 = A + (size_t)(bm * 128 + r0 + 64) * 1024 + kt * 32 + c0;
    const unsigned short* gb0 = Bt + (size_t)(bn * 128 + r0) * 1024 + kt * 32 + c0;
    const unsigned short* gb1 = Bt + (size_t)(bn * 128 + r0 + 64) * 1024 + kt * 32 + c0;
    __builtin_amdgcn_global_load_lds((GVT*)ga0, (LVT*)&As[b][tid * 8], 16, 0, 0);
    __builtin_amdgcn_global_load_lds((GVT*)ga1, (LVT*)&As[b][(tid + 256) * 8], 16, 0, 0);
    __builtin_amdgcn_global_load_lds((GVT*)gb0, (LVT*)&Bs[b][tid * 8], 16, 0, 0);
    __builtin_amdgcn_global_load_lds((GVT*)gb1, (LVT*)&Bs[b][(tid + 256) * 8], 16, 0, 0);
  };

  STAGE(0, 0);
  int cur = 0;
  for (int kt = 0; kt < 32; ++kt) {
    __syncthreads();                       // buf[cur] staged; prev reads done
    if (kt + 1 < 32) STAGE(cur ^ 1, kt + 1);
    bf16x8 af[4], bfr[4];
#pragma unroll
    for (int i = 0; i < 4; ++i) {
      af[i] = *reinterpret_cast<const bf16x8*>(&As[cur][(wr * 64 + i * 16 + lr) * 32 + hg * 8]);
      bfr[i] = *reinterpret_cast<const bf16x8*>(&Bs[cur][(wc * 64 + i * 16 + lr) * 32 + hg * 8]);
    }
    __builtin_amdgcn_s_setprio(1);
#pragma unroll
    for (int i = 0; i < 4; ++i)
#pragma unroll
      for (int j = 0; j < 4; ++j)
        acc[i][j] = __builtin_amdgcn_mfma_f32_16x16x32_bf16(af[i], bfr[j], acc[i][j], 0, 0, 0);
    __builtin_amdgcn_s_setprio(0);
    cur ^= 1;
  }

#pragma unroll
  for (int j = 0; j < 4; ++j) {
    const int col = bn * 128 + wc * 64 + j * 16 + lr;
    const float bv = bias[col];
    const int which = col >> 10;            // 0=q 1=k 2=v (uniform per wave)
    const int hh = (col >> 6) & 15;
    const int dh = col & 63;
    // q pre-scaled by SCALE * log2(e) so attention can use exp2 directly
    const float scl = which == 0 ? 0.18033688011112042f : 1.0f;
#pragma unroll
    for (int i = 0; i < 4; ++i) {
      if (which == 2) {
        const int row0 = bm * 128 + wr * 64 + i * 16 + hg * 4;   // 4 consecutive rows
        const int b = row0 >> 11, n0 = row0 & 2047;
        ushort4 vv;
        vv.x = f2bf(acc[i][j][0] + bv);
        vv.y = f2bf(acc[i][j][1] + bv);
        vv.z = f2bf(acc[i][j][2] + bv);
        vv.w = f2bf(acc[i][j][3] + bv);
        *reinterpret_cast<ushort4*>(
            &vtbuf[((size_t)((b * 16 + hh) * 64 + dh)) * 2048 + n0]) = vv;
      } else {
        unsigned short* dst = which == 0 ? qb : kbuf;
#pragma unroll
        for (int r = 0; r < 4; ++r) {
          const int row = bm * 128 + wr * 64 + i * 16 + hg * 4 + r;
          const int b = row >> 11, n = row & 2047;
          dst[((size_t)((b * 16 + hh) * 2048 + n)) * 64 + dh] = f2bf((acc[i][j][r] + bv) * scl);
        }
      }
    }
  }
}

// ---------------- Proj GEMM: out[4096][1024] fp32 = AObf @ Wproj^T + b ----------
__global__ __launch_bounds__(256, 2) void gemm_proj_kernel(
    const unsigned short* __restrict__ A,    // [4096][1024] bf16
    const unsigned short* __restrict__ Bt,   // [1024][1024] bf16
    const float* __restrict__ bias,          // [1024]
    float* __restrict__ out) {
  __shared__ __align__(16) unsigned short As[2][128 * 32];
  __shared__ __align__(16) unsigned short Bs[2][128 * 32];
  const int tid = threadIdx.x;
  const int lane = tid & 63;
  const int wid = tid >> 6;
  const int wr = wid >> 1, wc = wid & 1;
  // XCD swizzle: 256 blocks, 32 per XCD (4 bm-rows × 8 bn)
  const int lin = blockIdx.y * 8 + blockIdx.x;
  const int wg = (lin & 7) * 32 + (lin >> 3);
  const int bm = wg / 8, bn = wg % 8;
  const int lr = lane & 15, hg = lane >> 4;

  f32x4 acc[4][4] = {};
  const int r0 = tid >> 2;
  const int c0 = (tid & 3) * 8;

  auto STAGE = [&](int b, int kt) {
    const unsigned short* ga0 = A + (size_t)(bm * 128 + r0) * 1024 + kt * 32 + c0;
    const unsigned short* ga1 = A + (size_t)(bm * 128 + r0 + 64) * 1024 + kt * 32 + c0;
    const unsigned short* gb0 = Bt + (size_t)(bn * 128 + r0) * 1024 + kt * 32 + c0;
    const unsigned short* gb1 = Bt + (size_t)(bn * 128 + r0 + 64) * 1024 + kt * 32 + c0;
    __builtin_amdgcn_global_load_lds((GVT*)ga0, (LVT*)&As[b][tid * 8], 16, 0, 0);
    __builtin_amdgcn_global_load_lds((GVT*)ga1, (LVT*)&As[b][(tid + 256) * 8], 16, 0, 0);
    __builtin_amdgcn_global_load_lds((GVT*)gb0, (LVT*)&Bs[b][tid * 8], 16, 0, 0);
    __builtin_amdgcn_global_load_lds((GVT*)gb1, (LVT*)&Bs[b][(tid + 256) * 8], 16, 0, 0);
  };

  STAGE(0, 0);
  int cur = 0;
  for (int kt = 0; kt < 32; ++kt) {
    __syncthreads();
    if (kt + 1 < 32) STAGE(cur ^ 1, kt + 1);
    bf16x8 af[4], bfr[4];
#pragma unroll
    for (int i = 0; i < 4; ++i) {
      af[i] = *reinterpret_cast<const bf16x8*>(&As[cur][(wr * 64 + i * 16 + lr) * 32 + hg * 8]);
      bfr[i] = *reinterpret_cast<const bf16x8*>(&Bs[cur][(wc * 64 + i * 16 + lr) * 32 + hg * 8]);
    }
    __builtin_amdgcn_s_setprio(1);
#pragma unroll
    for (int i = 0; i < 4; ++i)
#pragma unroll
      for (int j = 0; j < 4; ++j)
        acc[i][j] = __builtin_amdgcn_mfma_f32_16x16x32_bf16(af[i], bfr[j], acc[i][j], 0, 0, 0);
    __builtin_amdgcn_s_setprio(0);
    cur ^= 1;
  }

#pragma unroll
  for (int j = 0; j < 4; ++j) {
    const int col = bn * 128 + wc * 64 + j * 16 + lr;
    const float bv = bias[col];
#pragma unroll
    for (int i = 0; i < 4; ++i)
#pragma unroll
      for (int r = 0; r < 4; ++r) {
        const int row = bm * 128 + wr * 64 + i * 16 + hg * 4 + r;
        out[(size_t)row * 1024 + col] = acc[i][j][r] + bv;
      }
  }
}

// ---------------- Flash attention, barrier-free: K and V^T fragments live in
// registers (global->VGPR, single-buffered prefetch); LDS only for the per-wave
// P round-trip. S^T = K*Q, O^T = V^T*P^T, exp2 softmax, defer-max. ----------
__global__ __launch_bounds__(256, 2) void attn_kernel(
    const unsigned short* __restrict__ qb,    // [32][2048][64] bf16, pre-scaled
    const unsigned short* __restrict__ kbuf,  // [32][2048][64]
    const unsigned short* __restrict__ vt,    // [32][64][2048]  (V^T per head)
    unsigned short* __restrict__ ao) {        // [4096][1024] bf16
  __shared__ __align__(16) unsigned short Ps[4][32][88];    // per-wave P[q_local][key]
  const int tid = threadIdx.x;
  const int lane = tid & 63;
  const int wid = tid >> 6;
  const int lr = lane & 15;
  const int hg = lane >> 4;                   // 0..3
  // XCD-bijective swizzle (512 blocks): all 16 q-tiles of a head on one XCD
  const int lin = blockIdx.y * 16 + blockIdx.x;
  const int wg = (lin & 7) * 64 + (lin >> 3);
  const int qt = wg & 15;                     // 0..15, 128 q-rows per block
  const int bh = wg >> 4;                     // 0..31
  const size_t hbase = (size_t)bh * SEQ * 64;

  // Q B-frags in registers: wave rows qt*128 + wid*32 + m*16 + lr
  bf16x8 qf[2][2];
#pragma unroll
  for (int m = 0; m < 2; ++m) {
    const unsigned short* qp =
        qb + hbase + (size_t)(qt * 128 + wid * 32 + m * 16 + lr) * 64 + hg * 8;
    qf[m][0] = *reinterpret_cast<const bf16x8*>(qp);
    qf[m][1] = *reinterpret_cast<const bf16x8*>(qp + 32);
  }

  // K / V^T fragments in registers (same bytes the old LDS reads returned)
  bf16x8 kf[4][2];   // kf[j][h] = K[kt*64 + j*16+lr][h*32 + hg*8 ..+7]
  bf16x8 vf[4][2];   // vf[jd][h] = V^T[jd*16+lr][kt*64 + h*32 + hg*8 ..+7]
  const unsigned short* kb0 = kbuf + hbase + (size_t)(lr)*64 + hg * 8;
  const unsigned short* vb0 = vt + hbase + (size_t)(lr)*2048 + hg * 8;
#pragma unroll
  for (int j = 0; j < 4; ++j) {
    kf[j][0] = *reinterpret_cast<const bf16x8*>(kb0 + (size_t)(j * 16) * 64);
    kf[j][1] = *reinterpret_cast<const bf16x8*>(kb0 + (size_t)(j * 16) * 64 + 32);
    vf[j][0] = *reinterpret_cast<const bf16x8*>(vb0 + (size_t)(j * 16) * 2048);
    vf[j][1] = *reinterpret_cast<const bf16x8*>(vb0 + (size_t)(j * 16) * 2048 + 32);
  }

  f32x4 accO[2][4] = {};                      // O^T: lane q=m*16+lr, d=jd*16+hg*4+r
  float m_run[2] = {-1e30f, -1e30f};
  float l_run[2] = {0.0f, 0.0f};

  for (int kt = 0; kt < 32; ++kt) {
    const int ktn = kt < 31 ? kt + 1 : 31;

    // S^T = K * Q : lane holds key=j*16+hg*4+r, q=m*16+lr  (log2-domain scores)
    f32x4 accT[2][4] = {};
    __builtin_amdgcn_s_setprio(1);
#pragma unroll
    for (int j = 0; j < 4; ++j) {
      accT[0][j] = __builtin_amdgcn_mfma_f32_16x16x32_bf16(kf[j][0], qf[0][0], accT[0][j], 0, 0, 0);
      accT[0][j] = __builtin_amdgcn_mfma_f32_16x16x32_bf16(kf[j][1], qf[0][1], accT[0][j], 0, 0, 0);
      accT[1][j] = __builtin_amdgcn_mfma_f32_16x16x32_bf16(kf[j][0], qf[1][0], accT[1][j], 0, 0, 0);
      accT[1][j] = __builtin_amdgcn_mfma_f32_16x16x32_bf16(kf[j][1], qf[1][1], accT[1][j], 0, 0, 0);
    }
    __builtin_amdgcn_s_setprio(0);

    // prefetch next K tile into kf (WAR on the mfmas above)
#pragma unroll
    for (int j = 0; j < 4; ++j) {
      kf[j][0] = *reinterpret_cast<const bf16x8*>(kb0 + (size_t)(ktn * 64 + j * 16) * 64);
      kf[j][1] = *reinterpret_cast<const bf16x8*>(kb0 + (size_t)(ktn * 64 + j * 16) * 64 + 32);
    }

    // online softmax in exp2 domain; lane owns q=m*16+lr
#pragma unroll
    for (int m = 0; m < 2; ++m) {
      float t0 = fmaxf(fmaxf(accT[m][0][0], accT[m][0][1]), fmaxf(accT[m][0][2], accT[m][0][3]));
      float t1 = fmaxf(fmaxf(accT[m][1][0], accT[m][1][1]), fmaxf(accT[m][1][2], accT[m][1][3]));
      float t2 = fmaxf(fmaxf(accT[m][2][0], accT[m][2][1]), fmaxf(accT[m][2][2], accT[m][2][3]));
      float t3 = fmaxf(fmaxf(accT[m][3][0], accT[m][3][1]), fmaxf(accT[m][3][2], accT[m][3][3]));
      float mt = fmaxf(fmaxf(t0, t1), fmaxf(t2, t3));
      mt = fmaxf(mt, __shfl_xor(mt, 16));
      mt = fmaxf(mt, __shfl_xor(mt, 32));
      if (__any(mt > m_run[m] + 8.0f)) {      // defer-max: P bounded by 2^8
        const float mnew = fmaxf(m_run[m], mt);
        const float crr = __builtin_amdgcn_exp2f(m_run[m] - mnew);
        m_run[m] = mnew;
        l_run[m] *= crr;
#pragma unroll
        for (int jd = 0; jd < 4; ++jd)
#pragma unroll
          for (int r = 0; r < 4; ++r) accO[m][jd][r] *= crr;
      }
      float ps0 = 0.f, ps1 = 0.f;
#pragma unroll
      for (int j = 0; j < 4; ++j) {
        const float p0 = __builtin_amdgcn_exp2f(accT[m][j][0] - m_run[m]);
        const float p1 = __builtin_amdgcn_exp2f(accT[m][j][1] - m_run[m]);
        const float p2 = __builtin_amdgcn_exp2f(accT[m][j][2] - m_run[m]);
        const float p3 = __builtin_amdgcn_exp2f(accT[m][j][3] - m_run[m]);
        ps0 += (p0 + p1);
        ps1 += (p2 + p3);
        uint2 w;
        w.x = pk_bf16(p0, p1);
        w.y = pk_bf16(p2, p3);
        *reinterpret_cast<uint2*>(&Ps[wid][m * 16 + lr][j * 16 + hg * 4]) = w;
      }
      float ps = ps0 + ps1;
      ps += __shfl_xor(ps, 16);
      ps += __shfl_xor(ps, 32);
      l_run[m] += ps;
    }

    // PV: O^T += V^T * P^T (B-frag of P^T == A-frag bytes of P)
    bf16x8 pB[2][2];
#pragma unroll
    for (int m = 0; m < 2; ++m) {
      pB[m][0] = *reinterpret_cast<const bf16x8*>(&Ps[wid][m * 16 + lr][hg * 8]);
      pB[m][1] = *reinterpret_cast<const bf16x8*>(&Ps[wid][m * 16 + lr][32 + hg * 8]);
    }
    __builtin_amdgcn_s_setprio(1);
#pragma unroll
    for (int jd = 0; jd < 4; ++jd) {
      accO[0][jd] = __builtin_amdgcn_mfma_f32_16x16x32_bf16(vf[jd][0], pB[0][0], accO[0][jd], 0, 0, 0);
      accO[0][jd] = __builtin_amdgcn_mfma_f32_16x16x32_bf16(vf[jd][1], pB[0][1], accO[0][jd], 0, 0, 0);
      accO[1][jd] = __builtin_amdgcn_mfma_f32_16x16x32_bf16(vf[jd][0], pB[1][0], accO[1][jd], 0, 0, 0);
      accO[1][jd] = __builtin_amdgcn_mfma_f32_16x16x32_bf16(vf[jd][1], pB[1][1], accO[1][jd], 0, 0, 0);
    }
    __builtin_amdgcn_s_setprio(0);

    // prefetch next V^T tile into vf
#pragma unroll
    for (int jd = 0; jd < 4; ++jd) {
      vf[jd][0] = *reinterpret_cast<const bf16x8*>(vb0 + (size_t)(jd * 16) * 2048 + ktn * 64);
      vf[jd][1] = *reinterpret_cast<const bf16x8*>(vb0 + (size_t)(jd * 16) * 2048 + ktn * 64 + 32);
    }
  }

  // epilogue: lane holds q=m*16+lr, d=jd*16+hg*4+r; l_run lives on the same lanes
  const int b = bh >> 4, hh = bh & 15;
#pragma unroll
  for (int m = 0; m < 2; ++m) {
    const float invl = 1.0f / l_run[m];
    const int qrow = qt * 128 + wid * 32 + m * 16 + lr;
    unsigned short* dst = ao + (size_t)(b * 2048 + qrow) * 1024 + hh * 64;
#pragma unroll
    for (int jd = 0; jd < 4; ++jd) {
      uint2 o;
      o.x = pk_bf16(accO[m][jd][0] * invl, accO[m][jd][1] * invl);
      o.y = pk_bf16(accO[m][jd][2] * invl, accO[m][jd][3] * invl);
      *reinterpret_cast<uint2*>(dst + jd * 16 + hg * 4) = o;
    }
  }
}

extern "C" void kernel_launch(void* const* d_in, const int* in_sizes, int n_in,
                              void* d_out, int out_size, void* d_ws, size_t ws_size,
                              hipStream_t stream) {
  const float* x = (const float*)d_in[0];
  const float* w_qkv = (const float*)d_in[1];
  const float* b_qkv = (const float*)d_in[2];
  const float* w_proj = (const float*)d_in[3];
  const float* b_proj = (const float*)d_in[4];
  float* out = (float*)d_out;
  char* ws = (char*)d_ws;
  unsigned short* x_bf = (unsigned short*)(ws);                   // [0, 8MB)
  unsigned short* ao_bf = (unsigned short*)(ws);                  // overlay, [0, 8MB)
  unsigned short* wq_bf = (unsigned short*)(ws + (8ull << 20));   // [8, 14MB)
  unsigned short* wp_bf = (unsigned short*)(ws + (14ull << 20));  // [14, 16MB)
  unsigned short* q_bf = (unsigned short*)(ws + (16ull << 20));   // [16, 24MB)
  unsigned short* k_bf = (unsigned short*)(ws + (24ull << 20));   // [24, 32MB)
  unsigned short* vt_bf = (unsigned short*)(ws + (32ull << 20));  // [32, 40MB)  V^T

  cvt3_kernel<<<2048, 256, 0, stream>>>(x, x_bf, 4096 * 1024 / 4,
                                        w_qkv, wq_bf, 3072 * 1024 / 4,
                                        w_proj, wp_bf, 1024 * 1024 / 4);
  gemm_qkv_kernel<<<dim3(24, 32), 256, 0, stream>>>(x_bf, wq_bf, b_qkv, q_bf, k_bf, vt_bf);
  attn_kernel<<<dim3(16, 32), 256, 0, stream>>>(q_bf, k_bf, vt_bf, ao_bf);
  gemm_proj_kernel<<<dim3(8, 32), 256, 0, stream>>>(ao_bf, wp_bf, b_proj, out);
}

// Round 6
// 130.424 us; speedup vs baseline: 1.4178x; 1.4178x over previous
//
#include <hip/hip_runtime.h>
#include <stdint.h>

#define SEQ 2048

typedef __attribute__((ext_vector_type(8))) short bf16x8;
typedef __attribute__((ext_vector_type(4))) float f32x4;
typedef __attribute__((ext_vector_type(4))) int i32x4;

typedef const __attribute__((address_space(1))) unsigned int GVT;
typedef __attribute__((address_space(3))) unsigned int LVT;

static __device__ __forceinline__ unsigned short f2bf(float f) {
  unsigned u = __builtin_bit_cast(unsigned, f);
  u += 0x7fffu + ((u >> 16) & 1u);
  return (unsigned short)(u >> 16);
}

static __device__ __forceinline__ unsigned pk_bf16(float lo, float hi) {
  unsigned r;
  asm("v_cvt_pk_bf16_f32 %0, %1, %2" : "=v"(r) : "v"(lo), "v"(hi));
  return r;
}

// one kernel converts x, w_qkv, w_proj (saves 2 launch overheads)
__global__ __launch_bounds__(256) void cvt3_kernel(
    const float* __restrict__ s0, unsigned short* __restrict__ d0, int n0,
    const float* __restrict__ s1, unsigned short* __restrict__ d1, int n1,
    const float* __restrict__ s2, unsigned short* __restrict__ d2, int n2) {
  int i = blockIdx.x * 256 + threadIdx.x;
  const int stride = gridDim.x * 256;
  const int total = n0 + n1 + n2;
  for (; i < total; i += stride) {
    const float* s;
    unsigned short* d;
    int k;
    if (i < n0) { s = s0; d = d0; k = i; }
    else if (i < n0 + n1) { s = s1; d = d1; k = i - n0; }
    else { s = s2; d = d2; k = i - n0 - n1; }
    float4 v = reinterpret_cast<const float4*>(s)[k];
    ushort4 o;
    o.x = f2bf(v.x); o.y = f2bf(v.y); o.z = f2bf(v.z); o.w = f2bf(v.w);
    reinterpret_cast<ushort4*>(d)[k] = o;
  }
}

// ---------------- QKV GEMM: C[4096][3072] = Xbf @ Wqkv^T, scatter to q/k/vt ----------
// q: [32][2048][64] (pre-scaled by SCALE*log2e); k: [32][2048][64]; vt: [32][64][2048]
__global__ __launch_bounds__(256, 2) void gemm_qkv_kernel(
    const unsigned short* __restrict__ A,    // [4096][1024] bf16
    const unsigned short* __restrict__ Bt,   // [3072][1024] bf16
    const float* __restrict__ bias,          // [3072]
    unsigned short* __restrict__ qb,
    unsigned short* __restrict__ kbuf,
    unsigned short* __restrict__ vtbuf) {
  __shared__ __align__(16) unsigned short As[2][128 * 32];
  __shared__ __align__(16) unsigned short Bs[2][128 * 32];
  const int tid = threadIdx.x;
  const int lane = tid & 63;
  const int wid = tid >> 6;
  const int wr = wid >> 1, wc = wid & 1;
  // XCD-bijective swizzle: 768 blocks, 768/8 = 96 per XCD (4 bm-rows each)
  const int lin = blockIdx.y * 24 + blockIdx.x;
  const int wg = (lin & 7) * 96 + (lin >> 3);
  const int bm = wg / 24, bn = wg % 24;
  const int lr = lane & 15, hg = lane >> 4;

  f32x4 acc[4][4] = {};

  const int r0 = tid >> 2;                 // staging row
  const int c0 = (tid & 3) * 8;            // staging col (elements)

  auto STAGE = [&](int b, int kt) {
    const unsigned short* ga0 = A + (size_t)(bm * 128 + r0) * 1024 + kt * 32 + c0;
    const unsigned short* ga1 = A + (size_t)(bm * 128 + r0 + 64) * 1024 + kt * 32 + c0;
    const unsigned short* gb0 = Bt + (size_t)(bn * 128 + r0) * 1024 + kt * 32 + c0;
    const unsigned short* gb1 = Bt + (size_t)(bn * 128 + r0 + 64) * 1024 + kt * 32 + c0;
    __builtin_amdgcn_global_load_lds((GVT*)ga0, (LVT*)&As[b][tid * 8], 16, 0, 0);
    __builtin_amdgcn_global_load_lds((GVT*)ga1, (LVT*)&As[b][(tid + 256) * 8], 16, 0, 0);
    __builtin_amdgcn_global_load_lds((GVT*)gb0, (LVT*)&Bs[b][tid * 8], 16, 0, 0);
    __builtin_amdgcn_global_load_lds((GVT*)gb1, (LVT*)&Bs[b][(tid + 256) * 8], 16, 0, 0);
  };

  STAGE(0, 0);
  int cur = 0;
  for (int kt = 0; kt < 32; ++kt) {
    __syncthreads();                       // buf[cur] staged; prev reads done
    if (kt + 1 < 32) STAGE(cur ^ 1, kt + 1);
    bf16x8 af[4], bfr[4];
#pragma unroll
    for (int i = 0; i < 4; ++i) {
      af[i] = *reinterpret_cast<const bf16x8*>(&As[cur][(wr * 64 + i * 16 + lr) * 32 + hg * 8]);
      bfr[i] = *reinterpret_cast<const bf16x8*>(&Bs[cur][(wc * 64 + i * 16 + lr) * 32 + hg * 8]);
    }
    __builtin_amdgcn_s_setprio(1);
#pragma unroll
    for (int i = 0; i < 4; ++i)
#pragma unroll
      for (int j = 0; j < 4; ++j)
        acc[i][j] = __builtin_amdgcn_mfma_f32_16x16x32_bf16(af[i], bfr[j], acc[i][j], 0, 0, 0);
    __builtin_amdgcn_s_setprio(0);
    cur ^= 1;
  }

#pragma unroll
  for (int j = 0; j < 4; ++j) {
    const int col = bn * 128 + wc * 64 + j * 16 + lr;
    const float bv = bias[col];
    const int which = col >> 10;            // 0=q 1=k 2=v (uniform per wave)
    const int hh = (col >> 6) & 15;
    const int dh = col & 63;
    // q pre-scaled by SCALE * log2(e) so attention can use exp2 directly
    const float scl = which == 0 ? 0.18033688011112042f : 1.0f;
#pragma unroll
    for (int i = 0; i < 4; ++i) {
      if (which == 2) {
        const int row0 = bm * 128 + wr * 64 + i * 16 + hg * 4;   // 4 consecutive rows
        const int b = row0 >> 11, n0 = row0 & 2047;
        ushort4 vv;
        vv.x = f2bf(acc[i][j][0] + bv);
        vv.y = f2bf(acc[i][j][1] + bv);
        vv.z = f2bf(acc[i][j][2] + bv);
        vv.w = f2bf(acc[i][j][3] + bv);
        *reinterpret_cast<ushort4*>(
            &vtbuf[((size_t)((b * 16 + hh) * 64 + dh)) * 2048 + n0]) = vv;
      } else {
        unsigned short* dst = which == 0 ? qb : kbuf;
#pragma unroll
        for (int r = 0; r < 4; ++r) {
          const int row = bm * 128 + wr * 64 + i * 16 + hg * 4 + r;
          const int b = row >> 11, n = row & 2047;
          dst[((size_t)((b * 16 + hh) * 2048 + n)) * 64 + dh] = f2bf((acc[i][j][r] + bv) * scl);
        }
      }
    }
  }
}

// ---------------- Proj GEMM: out[4096][1024] fp32 = AObf @ Wproj^T + b ----------
__global__ __launch_bounds__(256, 2) void gemm_proj_kernel(
    const unsigned short* __restrict__ A,    // [4096][1024] bf16
    const unsigned short* __restrict__ Bt,   // [1024][1024] bf16
    const float* __restrict__ bias,          // [1024]
    float* __restrict__ out) {
  __shared__ __align__(16) unsigned short As[2][128 * 32];
  __shared__ __align__(16) unsigned short Bs[2][128 * 32];
  const int tid = threadIdx.x;
  const int lane = tid & 63;
  const int wid = tid >> 6;
  const int wr = wid >> 1, wc = wid & 1;
  // XCD swizzle: 256 blocks, 32 per XCD (4 bm-rows × 8 bn)
  const int lin = blockIdx.y * 8 + blockIdx.x;
  const int wg = (lin & 7) * 32 + (lin >> 3);
  const int bm = wg / 8, bn = wg % 8;
  const int lr = lane & 15, hg = lane >> 4;

  f32x4 acc[4][4] = {};
  const int r0 = tid >> 2;
  const int c0 = (tid & 3) * 8;

  auto STAGE = [&](int b, int kt) {
    const unsigned short* ga0 = A + (size_t)(bm * 128 + r0) * 1024 + kt * 32 + c0;
    const unsigned short* ga1 = A + (size_t)(bm * 128 + r0 + 64) * 1024 + kt * 32 + c0;
    const unsigned short* gb0 = Bt + (size_t)(bn * 128 + r0) * 1024 + kt * 32 + c0;
    const unsigned short* gb1 = Bt + (size_t)(bn * 128 + r0 + 64) * 1024 + kt * 32 + c0;
    __builtin_amdgcn_global_load_lds((GVT*)ga0, (LVT*)&As[b][tid * 8], 16, 0, 0);
    __builtin_amdgcn_global_load_lds((GVT*)ga1, (LVT*)&As[b][(tid + 256) * 8], 16, 0, 0);
    __builtin_amdgcn_global_load_lds((GVT*)gb0, (LVT*)&Bs[b][tid * 8], 16, 0, 0);
    __builtin_amdgcn_global_load_lds((GVT*)gb1, (LVT*)&Bs[b][(tid + 256) * 8], 16, 0, 0);
  };

  STAGE(0, 0);
  int cur = 0;
  for (int kt = 0; kt < 32; ++kt) {
    __syncthreads();
    if (kt + 1 < 32) STAGE(cur ^ 1, kt + 1);
    bf16x8 af[4], bfr[4];
#pragma unroll
    for (int i = 0; i < 4; ++i) {
      af[i] = *reinterpret_cast<const bf16x8*>(&As[cur][(wr * 64 + i * 16 + lr) * 32 + hg * 8]);
      bfr[i] = *reinterpret_cast<const bf16x8*>(&Bs[cur][(wc * 64 + i * 16 + lr) * 32 + hg * 8]);
    }
    __builtin_amdgcn_s_setprio(1);
#pragma unroll
    for (int i = 0; i < 4; ++i)
#pragma unroll
      for (int j = 0; j < 4; ++j)
        acc[i][j] = __builtin_amdgcn_mfma_f32_16x16x32_bf16(af[i], bfr[j], acc[i][j], 0, 0, 0);
    __builtin_amdgcn_s_setprio(0);
    cur ^= 1;
  }

#pragma unroll
  for (int j = 0; j < 4; ++j) {
    const int col = bn * 128 + wc * 64 + j * 16 + lr;
    const float bv = bias[col];
#pragma unroll
    for (int i = 0; i < 4; ++i)
#pragma unroll
      for (int r = 0; r < 4; ++r) {
        const int row = bm * 128 + wr * 64 + i * 16 + hg * 4 + r;
        out[(size_t)row * 1024 + col] = acc[i][j][r] + bv;
      }
  }
}

// ---------------- Flash attention: LDS-staged K/V (dbuf, swizzled), S^T = K*Q,
// O^T = V^T*P^T, exp2 softmax, defer-max, P redistributed IN-REGISTER via
// v_permlane16/32_swap (no P LDS round-trip). ----------
__global__ __launch_bounds__(256, 2) void attn_kernel(
    const unsigned short* __restrict__ qb,    // [32][2048][64] bf16, pre-scaled
    const unsigned short* __restrict__ kbuf,  // [32][2048][64]
    const unsigned short* __restrict__ vt,    // [32][64][2048]  (V^T per head)
    unsigned short* __restrict__ ao) {        // [4096][1024] bf16
  __shared__ __align__(16) unsigned short Ks[2][64 * 64];   // [key][d], slot-XOR swizzled
  __shared__ __align__(16) unsigned short Vs[2][64 * 64];   // [d][key], slot-XOR swizzled
  const int tid = threadIdx.x;
  const int lane = tid & 63;
  const int wid = tid >> 6;
  const int lr = lane & 15;
  const int hg = lane >> 4;                   // 0..3
  // XCD-bijective swizzle (512 blocks): all 16 q-tiles of a head on one XCD
  const int lin = blockIdx.y * 16 + blockIdx.x;
  const int wg = (lin & 7) * 64 + (lin >> 3);
  const int qt = wg & 15;                     // 0..15, 128 q-rows per block
  const int bh = wg >> 4;                     // 0..31
  const size_t hbase = (size_t)bh * SEQ * 64;

  // Q B-frags in registers: wave rows qt*128 + wid*32 + m*16 + lr
  bf16x8 qf[2][2];
#pragma unroll
  for (int m = 0; m < 2; ++m) {
    const unsigned short* qp =
        qb + hbase + (size_t)(qt * 128 + wid * 32 + m * 16 + lr) * 64 + hg * 8;
    qf[m][0] = *reinterpret_cast<const bf16x8*>(qp);
    qf[m][1] = *reinterpret_cast<const bf16x8*>(qp + 32);
  }

  f32x4 accO[2][4] = {};                      // O^T: lane q=m*16+lr, d=jd*16+hg*4+r
  float m_run[2] = {-1e30f, -1e30f};
  float l_run[2] = {0.0f, 0.0f};

  auto STAGE = [&](int b, int kt) {
#pragma unroll
    for (int c = 0; c < 2; ++c) {
      const int t = tid + c * 256;            // chunk 0..511
      const int row = t >> 3;                 // 0..63
      const int sw = ((t & 7) ^ (row & 7)) * 8;  // inverse-swizzled source slot
      const unsigned short* gk = kbuf + hbase + (size_t)(kt * 64 + row) * 64 + sw;
      __builtin_amdgcn_global_load_lds((GVT*)gk, (LVT*)&Ks[b][t * 8], 16, 0, 0);
      const unsigned short* gv = vt + hbase + (size_t)row * 2048 + kt * 64 + sw;
      __builtin_amdgcn_global_load_lds((GVT*)gv, (LVT*)&Vs[b][t * 8], 16, 0, 0);
    }
  };

  STAGE(0, 0);
  int cur = 0;
  const int sw0 = (hg ^ (lr & 7)) * 8;        // swizzled slot, k-chunk 0
  const int sw1 = ((hg + 4) ^ (lr & 7)) * 8;  // swizzled slot, k-chunk 1

  for (int kt = 0; kt < 32; ++kt) {
    __syncthreads();                          // buf[cur] staged; prev-tile reads done
    if (kt + 1 < 32) STAGE(cur ^ 1, kt + 1);

    // S^T = K * Q : lane holds key=j*16+hg*4+r, q=m*16+lr  (log2-domain scores)
    f32x4 accT[2][4] = {};
    __builtin_amdgcn_s_setprio(1);
#pragma unroll
    for (int j = 0; j < 4; ++j) {
      const bf16x8 kf0 = *reinterpret_cast<const bf16x8*>(&Ks[cur][(j * 16 + lr) * 64 + sw0]);
      const bf16x8 kf1 = *reinterpret_cast<const bf16x8*>(&Ks[cur][(j * 16 + lr) * 64 + sw1]);
      accT[0][j] = __builtin_amdgcn_mfma_f32_16x16x32_bf16(kf0, qf[0][0], accT[0][j], 0, 0, 0);
      accT[0][j] = __builtin_amdgcn_mfma_f32_16x16x32_bf16(kf1, qf[0][1], accT[0][j], 0, 0, 0);
      accT[1][j] = __builtin_amdgcn_mfma_f32_16x16x32_bf16(kf0, qf[1][0], accT[1][j], 0, 0, 0);
      accT[1][j] = __builtin_amdgcn_mfma_f32_16x16x32_bf16(kf1, qf[1][1], accT[1][j], 0, 0, 0);
    }
    __builtin_amdgcn_s_setprio(0);

    // online softmax in exp2 domain; lane owns q=m*16+lr.  P -> bf16 B-frag fully
    // in-register: cvt_pk pairs, then permlane32/16 swaps redistribute across the
    // 4 hg-groups (derivation: B-frag key=hg*8+e comes from source hg'=(hg&1)*2+{0,1},
    // j=h*2+(hg>>1); two swap rounds realize exactly this).
    bf16x8 pB[2][2];
#pragma unroll
    for (int m = 0; m < 2; ++m) {
      float t0 = fmaxf(fmaxf(accT[m][0][0], accT[m][0][1]), fmaxf(accT[m][0][2], accT[m][0][3]));
      float t1 = fmaxf(fmaxf(accT[m][1][0], accT[m][1][1]), fmaxf(accT[m][1][2], accT[m][1][3]));
      float t2 = fmaxf(fmaxf(accT[m][2][0], accT[m][2][1]), fmaxf(accT[m][2][2], accT[m][2][3]));
      float t3 = fmaxf(fmaxf(accT[m][3][0], accT[m][3][1]), fmaxf(accT[m][3][2], accT[m][3][3]));
      float mt = fmaxf(fmaxf(t0, t1), fmaxf(t2, t3));
      mt = fmaxf(mt, __shfl_xor(mt, 16));
      mt = fmaxf(mt, __shfl_xor(mt, 32));
      if (__any(mt > m_run[m] + 8.0f)) {      // defer-max: P bounded by 2^8
        const float mnew = fmaxf(m_run[m], mt);
        const float crr = __builtin_amdgcn_exp2f(m_run[m] - mnew);
        m_run[m] = mnew;
        l_run[m] *= crr;
#pragma unroll
        for (int jd = 0; jd < 4; ++jd)
#pragma unroll
          for (int r = 0; r < 4; ++r) accO[m][jd][r] *= crr;
      }
      unsigned w[4][2];
      float ps0 = 0.f, ps1 = 0.f;
#pragma unroll
      for (int j = 0; j < 4; ++j) {
        const float p0 = __builtin_amdgcn_exp2f(accT[m][j][0] - m_run[m]);
        const float p1 = __builtin_amdgcn_exp2f(accT[m][j][1] - m_run[m]);
        const float p2 = __builtin_amdgcn_exp2f(accT[m][j][2] - m_run[m]);
        const float p3 = __builtin_amdgcn_exp2f(accT[m][j][3] - m_run[m]);
        ps0 += (p0 + p1);
        ps1 += (p2 + p3);
        w[j][0] = pk_bf16(p0, p1);
        w[j][1] = pk_bf16(p2, p3);
      }
      float ps = ps0 + ps1;
      ps += __shfl_xor(ps, 16);
      ps += __shfl_xor(ps, 32);
      l_run[m] += ps;
#pragma unroll
      for (int h = 0; h < 2; ++h) {
        unsigned e0 = w[2 * h][0], e1 = w[2 * h][1];
        unsigned f0 = w[2 * h + 1][0], f1 = w[2 * h + 1][1];
        asm("v_permlane32_swap_b32 %0, %1" : "+v"(e0), "+v"(f0));
        asm("v_permlane32_swap_b32 %0, %1" : "+v"(e1), "+v"(f1));
        asm("v_permlane16_swap_b32 %0, %1" : "+v"(e0), "+v"(f0));
        asm("v_permlane16_swap_b32 %0, %1" : "+v"(e1), "+v"(f1));
        const i32x4 pw = {(int)e0, (int)e1, (int)f0, (int)f1};
        pB[m][h] = __builtin_bit_cast(bf16x8, pw);
      }
    }

    // PV: O^T += V^T * P^T (B-frag of P^T assembled above, register-resident)
    __builtin_amdgcn_s_setprio(1);
#pragma unroll
    for (int jd = 0; jd < 4; ++jd) {
      const bf16x8 v0 = *reinterpret_cast<const bf16x8*>(&Vs[cur][(jd * 16 + lr) * 64 + sw0]);
      const bf16x8 v1 = *reinterpret_cast<const bf16x8*>(&Vs[cur][(jd * 16 + lr) * 64 + sw1]);
      accO[0][jd] = __builtin_amdgcn_mfma_f32_16x16x32_bf16(v0, pB[0][0], accO[0][jd], 0, 0, 0);
      accO[0][jd] = __builtin_amdgcn_mfma_f32_16x16x32_bf16(v1, pB[0][1], accO[0][jd], 0, 0, 0);
      accO[1][jd] = __builtin_amdgcn_mfma_f32_16x16x32_bf16(v0, pB[1][0], accO[1][jd], 0, 0, 0);
      accO[1][jd] = __builtin_amdgcn_mfma_f32_16x16x32_bf16(v1, pB[1][1], accO[1][jd], 0, 0, 0);
    }
    __builtin_amdgcn_s_setprio(0);
    cur ^= 1;
  }

  // epilogue: lane holds q=m*16+lr, d=jd*16+hg*4+r; l_run lives on the same lanes
  const int b = bh >> 4, hh = bh & 15;
#pragma unroll
  for (int m = 0; m < 2; ++m) {
    const float invl = 1.0f / l_run[m];
    const int qrow = qt * 128 + wid * 32 + m * 16 + lr;
    unsigned short* dst = ao + (size_t)(b * 2048 + qrow) * 1024 + hh * 64;
#pragma unroll
    for (int jd = 0; jd < 4; ++jd) {
      uint2 o;
      o.x = pk_bf16(accO[m][jd][0] * invl, accO[m][jd][1] * invl);
      o.y = pk_bf16(accO[m][jd][2] * invl, accO[m][jd][3] * invl);
      *reinterpret_cast<uint2*>(dst + jd * 16 + hg * 4) = o;
    }
  }
}

extern "C" void kernel_launch(void* const* d_in, const int* in_sizes, int n_in,
                              void* d_out, int out_size, void* d_ws, size_t ws_size,
                              hipStream_t stream) {
  const float* x = (const float*)d_in[0];
  const float* w_qkv = (const float*)d_in[1];
  const float* b_qkv = (const float*)d_in[2];
  const float* w_proj = (const float*)d_in[3];
  const float* b_proj = (const float*)d_in[4];
  float* out = (float*)d_out;
  char* ws = (char*)d_ws;
  unsigned short* x_bf = (unsigned short*)(ws);                   // [0, 8MB)
  unsigned short* ao_bf = (unsigned short*)(ws);                  // overlay, [0, 8MB)
  unsigned short* wq_bf = (unsigned short*)(ws + (8ull << 20));   // [8, 14MB)
  unsigned short* wp_bf = (unsigned short*)(ws + (14ull << 20));  // [14, 16MB)
  unsigned short* q_bf = (unsigned short*)(ws + (16ull << 20));   // [16, 24MB)
  unsigned short* k_bf = (unsigned short*)(ws + (24ull << 20));   // [24, 32MB)
  unsigned short* vt_bf = (unsigned short*)(ws + (32ull << 20));  // [32, 40MB)  V^T

  cvt3_kernel<<<2048, 256, 0, stream>>>(x, x_bf, 4096 * 1024 / 4,
                                        w_qkv, wq_bf, 3072 * 1024 / 4,
                                        w_proj, wp_bf, 1024 * 1024 / 4);
  gemm_qkv_kernel<<<dim3(24, 32), 256, 0, stream>>>(x_bf, wq_bf, b_qkv, q_bf, k_bf, vt_bf);
  attn_kernel<<<dim3(16, 32), 256, 0, stream>>>(q_bf, k_bf, vt_bf, ao_bf);
  gemm_proj_kernel<<<dim3(8, 32), 256, 0, stream>>>(ao_bf, wp_bf, b_proj, out);
}

// Round 7
// 125.616 us; speedup vs baseline: 1.4721x; 1.0383x over previous
//
#include <hip/hip_runtime.h>
#include <stdint.h>

#define SEQ 2048

typedef __attribute__((ext_vector_type(8))) short bf16x8;
typedef __attribute__((ext_vector_type(4))) float f32x4;
typedef __attribute__((ext_vector_type(4))) int i32x4;

typedef const __attribute__((address_space(1))) unsigned int GVT;
typedef __attribute__((address_space(3))) unsigned int LVT;

static __device__ __forceinline__ unsigned short f2bf(float f) {
  unsigned u = __builtin_bit_cast(unsigned, f);
  u += 0x7fffu + ((u >> 16) & 1u);
  return (unsigned short)(u >> 16);
}

static __device__ __forceinline__ unsigned pk_bf16(float lo, float hi) {
  unsigned r;
  asm("v_cvt_pk_bf16_f32 %0, %1, %2" : "=v"(r) : "v"(lo), "v"(hi));
  return r;
}

// one kernel converts x, w_qkv, w_proj (saves 2 launch overheads)
__global__ __launch_bounds__(256) void cvt3_kernel(
    const float* __restrict__ s0, unsigned short* __restrict__ d0, int n0,
    const float* __restrict__ s1, unsigned short* __restrict__ d1, int n1,
    const float* __restrict__ s2, unsigned short* __restrict__ d2, int n2) {
  int i = blockIdx.x * 256 + threadIdx.x;
  const int stride = gridDim.x * 256;
  const int total = n0 + n1 + n2;
  for (; i < total; i += stride) {
    const float* s;
    unsigned short* d;
    int k;
    if (i < n0) { s = s0; d = d0; k = i; }
    else if (i < n0 + n1) { s = s1; d = d1; k = i - n0; }
    else { s = s2; d = d2; k = i - n0 - n1; }
    float4 v = reinterpret_cast<const float4*>(s)[k];
    ushort4 o;
    o.x = f2bf(v.x); o.y = f2bf(v.y); o.z = f2bf(v.z); o.w = f2bf(v.w);
    reinterpret_cast<ushort4*>(d)[k] = o;
  }
}

// ---------------- QKV GEMM: C[4096][3072] = Xbf @ Wqkv^T, scatter to q/k/vt ----------
// q: [32][2048][64] (pre-scaled by SCALE*log2e); k: [32][2048][64]; vt: [32][64][2048]
__global__ __launch_bounds__(256, 2) void gemm_qkv_kernel(
    const unsigned short* __restrict__ A,    // [4096][1024] bf16
    const unsigned short* __restrict__ Bt,   // [3072][1024] bf16
    const float* __restrict__ bias,          // [3072]
    unsigned short* __restrict__ qb,
    unsigned short* __restrict__ kbuf,
    unsigned short* __restrict__ vtbuf) {
  __shared__ __align__(16) unsigned short As[2][128 * 32];
  __shared__ __align__(16) unsigned short Bs[2][128 * 32];
  const int tid = threadIdx.x;
  const int lane = tid & 63;
  const int wid = tid >> 6;
  const int wr = wid >> 1, wc = wid & 1;
  // XCD-bijective swizzle: 768 blocks, 768/8 = 96 per XCD (4 bm-rows each)
  const int lin = blockIdx.y * 24 + blockIdx.x;
  const int wg = (lin & 7) * 96 + (lin >> 3);
  const int bm = wg / 24, bn = wg % 24;
  const int lr = lane & 15, hg = lane >> 4;

  f32x4 acc[4][4] = {};

  const int r0 = tid >> 2;                 // staging row
  const int c0 = (tid & 3) * 8;            // staging col (elements)

  auto STAGE = [&](int b, int kt) {
    const unsigned short* ga0 = A + (size_t)(bm * 128 + r0) * 1024 + kt * 32 + c0;
    const unsigned short* ga1 = A + (size_t)(bm * 128 + r0 + 64) * 1024 + kt * 32 + c0;
    const unsigned short* gb0 = Bt + (size_t)(bn * 128 + r0) * 1024 + kt * 32 + c0;
    const unsigned short* gb1 = Bt + (size_t)(bn * 128 + r0 + 64) * 1024 + kt * 32 + c0;
    __builtin_amdgcn_global_load_lds((GVT*)ga0, (LVT*)&As[b][tid * 8], 16, 0, 0);
    __builtin_amdgcn_global_load_lds((GVT*)ga1, (LVT*)&As[b][(tid + 256) * 8], 16, 0, 0);
    __builtin_amdgcn_global_load_lds((GVT*)gb0, (LVT*)&Bs[b][tid * 8], 16, 0, 0);
    __builtin_amdgcn_global_load_lds((GVT*)gb1, (LVT*)&Bs[b][(tid + 256) * 8], 16, 0, 0);
  };

  STAGE(0, 0);
  int cur = 0;
  for (int kt = 0; kt < 32; ++kt) {
    __syncthreads();                       // buf[cur] staged; prev reads done
    if (kt + 1 < 32) STAGE(cur ^ 1, kt + 1);
    bf16x8 af[4], bfr[4];
#pragma unroll
    for (int i = 0; i < 4; ++i) {
      af[i] = *reinterpret_cast<const bf16x8*>(&As[cur][(wr * 64 + i * 16 + lr) * 32 + hg * 8]);
      bfr[i] = *reinterpret_cast<const bf16x8*>(&Bs[cur][(wc * 64 + i * 16 + lr) * 32 + hg * 8]);
    }
    __builtin_amdgcn_s_setprio(1);
#pragma unroll
    for (int i = 0; i < 4; ++i)
#pragma unroll
      for (int j = 0; j < 4; ++j)
        acc[i][j] = __builtin_amdgcn_mfma_f32_16x16x32_bf16(af[i], bfr[j], acc[i][j], 0, 0, 0);
    __builtin_amdgcn_s_setprio(0);
    cur ^= 1;
  }

#pragma unroll
  for (int j = 0; j < 4; ++j) {
    const int col = bn * 128 + wc * 64 + j * 16 + lr;
    const float bv = bias[col];
    const int which = col >> 10;            // 0=q 1=k 2=v (uniform per wave)
    const int hh = (col >> 6) & 15;
    const int dh = col & 63;
    // q pre-scaled by SCALE * log2(e) so attention can use exp2 directly
    const float scl = which == 0 ? 0.18033688011112042f : 1.0f;
#pragma unroll
    for (int i = 0; i < 4; ++i) {
      if (which == 2) {
        const int row0 = bm * 128 + wr * 64 + i * 16 + hg * 4;   // 4 consecutive rows
        const int b = row0 >> 11, n0 = row0 & 2047;
        ushort4 vv;
        vv.x = f2bf(acc[i][j][0] + bv);
        vv.y = f2bf(acc[i][j][1] + bv);
        vv.z = f2bf(acc[i][j][2] + bv);
        vv.w = f2bf(acc[i][j][3] + bv);
        *reinterpret_cast<ushort4*>(
            &vtbuf[((size_t)((b * 16 + hh) * 64 + dh)) * 2048 + n0]) = vv;
      } else {
        unsigned short* dst = which == 0 ? qb : kbuf;
#pragma unroll
        for (int r = 0; r < 4; ++r) {
          const int row = bm * 128 + wr * 64 + i * 16 + hg * 4 + r;
          const int b = row >> 11, n = row & 2047;
          dst[((size_t)((b * 16 + hh) * 2048 + n)) * 64 + dh] = f2bf((acc[i][j][r] + bv) * scl);
        }
      }
    }
  }
}

// ---------------- Proj GEMM: out[4096][1024] fp32 = AObf @ Wproj^T + b ----------
__global__ __launch_bounds__(256, 2) void gemm_proj_kernel(
    const unsigned short* __restrict__ A,    // [4096][1024] bf16
    const unsigned short* __restrict__ Bt,   // [1024][1024] bf16
    const float* __restrict__ bias,          // [1024]
    float* __restrict__ out) {
  __shared__ __align__(16) unsigned short As[2][128 * 32];
  __shared__ __align__(16) unsigned short Bs[2][128 * 32];
  const int tid = threadIdx.x;
  const int lane = tid & 63;
  const int wid = tid >> 6;
  const int wr = wid >> 1, wc = wid & 1;
  // XCD swizzle: 256 blocks, 32 per XCD (4 bm-rows × 8 bn)
  const int lin = blockIdx.y * 8 + blockIdx.x;
  const int wg = (lin & 7) * 32 + (lin >> 3);
  const int bm = wg / 8, bn = wg % 8;
  const int lr = lane & 15, hg = lane >> 4;

  f32x4 acc[4][4] = {};
  const int r0 = tid >> 2;
  const int c0 = (tid & 3) * 8;

  auto STAGE = [&](int b, int kt) {
    const unsigned short* ga0 = A + (size_t)(bm * 128 + r0) * 1024 + kt * 32 + c0;
    const unsigned short* ga1 = A + (size_t)(bm * 128 + r0 + 64) * 1024 + kt * 32 + c0;
    const unsigned short* gb0 = Bt + (size_t)(bn * 128 + r0) * 1024 + kt * 32 + c0;
    const unsigned short* gb1 = Bt + (size_t)(bn * 128 + r0 + 64) * 1024 + kt * 32 + c0;
    __builtin_amdgcn_global_load_lds((GVT*)ga0, (LVT*)&As[b][tid * 8], 16, 0, 0);
    __builtin_amdgcn_global_load_lds((GVT*)ga1, (LVT*)&As[b][(tid + 256) * 8], 16, 0, 0);
    __builtin_amdgcn_global_load_lds((GVT*)gb0, (LVT*)&Bs[b][tid * 8], 16, 0, 0);
    __builtin_amdgcn_global_load_lds((GVT*)gb1, (LVT*)&Bs[b][(tid + 256) * 8], 16, 0, 0);
  };

  STAGE(0, 0);
  int cur = 0;
  for (int kt = 0; kt < 32; ++kt) {
    __syncthreads();
    if (kt + 1 < 32) STAGE(cur ^ 1, kt + 1);
    bf16x8 af[4], bfr[4];
#pragma unroll
    for (int i = 0; i < 4; ++i) {
      af[i] = *reinterpret_cast<const bf16x8*>(&As[cur][(wr * 64 + i * 16 + lr) * 32 + hg * 8]);
      bfr[i] = *reinterpret_cast<const bf16x8*>(&Bs[cur][(wc * 64 + i * 16 + lr) * 32 + hg * 8]);
    }
    __builtin_amdgcn_s_setprio(1);
#pragma unroll
    for (int i = 0; i < 4; ++i)
#pragma unroll
      for (int j = 0; j < 4; ++j)
        acc[i][j] = __builtin_amdgcn_mfma_f32_16x16x32_bf16(af[i], bfr[j], acc[i][j], 0, 0, 0);
    __builtin_amdgcn_s_setprio(0);
    cur ^= 1;
  }

#pragma unroll
  for (int j = 0; j < 4; ++j) {
    const int col = bn * 128 + wc * 64 + j * 16 + lr;
    const float bv = bias[col];
#pragma unroll
    for (int i = 0; i < 4; ++i)
#pragma unroll
      for (int r = 0; r < 4; ++r) {
        const int row = bm * 128 + wr * 64 + i * 16 + hg * 4 + r;
        out[(size_t)row * 1024 + col] = acc[i][j][r] + bv;
      }
  }
}

// ---------------- Flash attention: 8 waves / 512 threads per block (4 waves/SIMD
// for TLP), LDS-staged K/V (dbuf, swizzled), S^T = K*Q, O^T = V^T*P^T, exp2
// softmax, defer-max, in-register P redistribution via permlane swaps. ----------
__global__ __launch_bounds__(512, 4) void attn_kernel(
    const unsigned short* __restrict__ qb,    // [32][2048][64] bf16, pre-scaled
    const unsigned short* __restrict__ kbuf,  // [32][2048][64]
    const unsigned short* __restrict__ vt,    // [32][64][2048]  (V^T per head)
    unsigned short* __restrict__ ao) {        // [4096][1024] bf16
  __shared__ __align__(16) unsigned short Ks[2][64 * 64];   // [key][d], slot-XOR swizzled
  __shared__ __align__(16) unsigned short Vs[2][64 * 64];   // [d][key], slot-XOR swizzled
  const int tid = threadIdx.x;
  const int lane = tid & 63;
  const int wid = tid >> 6;                   // 0..7
  const int lr = lane & 15;
  const int hg = lane >> 4;                   // 0..3
  // XCD-bijective swizzle (512 blocks): all 16 q-tiles of a head on one XCD
  const int lin = blockIdx.y * 16 + blockIdx.x;
  const int wg = (lin & 7) * 64 + (lin >> 3);
  const int qt = wg & 15;                     // 0..15, 128 q-rows per block
  const int bh = wg >> 4;                     // 0..31
  const size_t hbase = (size_t)bh * SEQ * 64;

  // Q B-frags in registers: this wave's 16 q-rows = qt*128 + wid*16 + lr
  bf16x8 qf[2];
  {
    const unsigned short* qp =
        qb + hbase + (size_t)(qt * 128 + wid * 16 + lr) * 64 + hg * 8;
    qf[0] = *reinterpret_cast<const bf16x8*>(qp);
    qf[1] = *reinterpret_cast<const bf16x8*>(qp + 32);
  }

  f32x4 accO[4] = {};                         // O^T: lane q=lr, d=jd*16+hg*4+r
  float m_run = -1e30f;
  float l_run = 0.0f;

  auto STAGE = [&](int b, int kt) {
    const int row = tid >> 3;                 // 0..63
    const int sw = ((tid & 7) ^ (row & 7)) * 8;  // inverse-swizzled source slot
    const unsigned short* gk = kbuf + hbase + (size_t)(kt * 64 + row) * 64 + sw;
    __builtin_amdgcn_global_load_lds((GVT*)gk, (LVT*)&Ks[b][tid * 8], 16, 0, 0);
    const unsigned short* gv = vt + hbase + (size_t)row * 2048 + kt * 64 + sw;
    __builtin_amdgcn_global_load_lds((GVT*)gv, (LVT*)&Vs[b][tid * 8], 16, 0, 0);
  };

  STAGE(0, 0);
  int cur = 0;
  const int sw0 = (hg ^ (lr & 7)) * 8;        // swizzled slot, k-chunk 0
  const int sw1 = ((hg + 4) ^ (lr & 7)) * 8;  // swizzled slot, k-chunk 1

  for (int kt = 0; kt < 32; ++kt) {
    __syncthreads();                          // buf[cur] staged; prev-tile reads done
    if (kt + 1 < 32) STAGE(cur ^ 1, kt + 1);

    // S^T = K * Q : lane holds key=j*16+hg*4+r, q=lr  (log2-domain scores)
    f32x4 accT[4] = {};
    __builtin_amdgcn_s_setprio(1);
#pragma unroll
    for (int j = 0; j < 4; ++j) {
      const bf16x8 kf0 = *reinterpret_cast<const bf16x8*>(&Ks[cur][(j * 16 + lr) * 64 + sw0]);
      const bf16x8 kf1 = *reinterpret_cast<const bf16x8*>(&Ks[cur][(j * 16 + lr) * 64 + sw1]);
      accT[j] = __builtin_amdgcn_mfma_f32_16x16x32_bf16(kf0, qf[0], accT[j], 0, 0, 0);
      accT[j] = __builtin_amdgcn_mfma_f32_16x16x32_bf16(kf1, qf[1], accT[j], 0, 0, 0);
    }
    __builtin_amdgcn_s_setprio(0);

    // online softmax in exp2 domain; lane owns q=lr (16 keys here; union over
    // hg groups = 64 keys via two xor-shuffles)
    bf16x8 pB[2];
    {
      float t0 = fmaxf(fmaxf(accT[0][0], accT[0][1]), fmaxf(accT[0][2], accT[0][3]));
      float t1 = fmaxf(fmaxf(accT[1][0], accT[1][1]), fmaxf(accT[1][2], accT[1][3]));
      float t2 = fmaxf(fmaxf(accT[2][0], accT[2][1]), fmaxf(accT[2][2], accT[2][3]));
      float t3 = fmaxf(fmaxf(accT[3][0], accT[3][1]), fmaxf(accT[3][2], accT[3][3]));
      float mt = fmaxf(fmaxf(t0, t1), fmaxf(t2, t3));
      mt = fmaxf(mt, __shfl_xor(mt, 16));
      mt = fmaxf(mt, __shfl_xor(mt, 32));
      if (__any(mt > m_run + 8.0f)) {         // defer-max: P bounded by 2^8
        const float mnew = fmaxf(m_run, mt);
        const float crr = __builtin_amdgcn_exp2f(m_run - mnew);
        m_run = mnew;
        l_run *= crr;
#pragma unroll
        for (int jd = 0; jd < 4; ++jd)
#pragma unroll
          for (int r = 0; r < 4; ++r) accO[jd][r] *= crr;
      }
      unsigned w[4][2];
      float ps0 = 0.f, ps1 = 0.f;
#pragma unroll
      for (int j = 0; j < 4; ++j) {
        const float p0 = __builtin_amdgcn_exp2f(accT[j][0] - m_run);
        const float p1 = __builtin_amdgcn_exp2f(accT[j][1] - m_run);
        const float p2 = __builtin_amdgcn_exp2f(accT[j][2] - m_run);
        const float p3 = __builtin_amdgcn_exp2f(accT[j][3] - m_run);
        ps0 += (p0 + p1);
        ps1 += (p2 + p3);
        w[j][0] = pk_bf16(p0, p1);
        w[j][1] = pk_bf16(p2, p3);
      }
      float ps = ps0 + ps1;
      ps += __shfl_xor(ps, 16);
      ps += __shfl_xor(ps, 32);
      l_run += ps;
      // redistribute P across hg groups to B-frag layout (pure VALU, no LDS)
#pragma unroll
      for (int h = 0; h < 2; ++h) {
        unsigned e0 = w[2 * h][0], e1 = w[2 * h][1];
        unsigned f0 = w[2 * h + 1][0], f1 = w[2 * h + 1][1];
        asm("v_permlane32_swap_b32 %0, %1" : "+v"(e0), "+v"(f0));
        asm("v_permlane32_swap_b32 %0, %1" : "+v"(e1), "+v"(f1));
        asm("v_permlane16_swap_b32 %0, %1" : "+v"(e0), "+v"(f0));
        asm("v_permlane16_swap_b32 %0, %1" : "+v"(e1), "+v"(f1));
        const i32x4 pw = {(int)e0, (int)e1, (int)f0, (int)f1};
        pB[h] = __builtin_bit_cast(bf16x8, pw);
      }
    }

    // PV: O^T += V^T * P^T (B-frag of P^T assembled above, register-resident)
    __builtin_amdgcn_s_setprio(1);
#pragma unroll
    for (int jd = 0; jd < 4; ++jd) {
      const bf16x8 v0 = *reinterpret_cast<const bf16x8*>(&Vs[cur][(jd * 16 + lr) * 64 + sw0]);
      const bf16x8 v1 = *reinterpret_cast<const bf16x8*>(&Vs[cur][(jd * 16 + lr) * 64 + sw1]);
      accO[jd] = __builtin_amdgcn_mfma_f32_16x16x32_bf16(v0, pB[0], accO[jd], 0, 0, 0);
      accO[jd] = __builtin_amdgcn_mfma_f32_16x16x32_bf16(v1, pB[1], accO[jd], 0, 0, 0);
    }
    __builtin_amdgcn_s_setprio(0);
    cur ^= 1;
  }

  // epilogue: lane holds q=lr, d=jd*16+hg*4+r
  const int b = bh >> 4, hh = bh & 15;
  {
    const float invl = 1.0f / l_run;
    const int qrow = qt * 128 + wid * 16 + lr;
    unsigned short* dst = ao + (size_t)(b * 2048 + qrow) * 1024 + hh * 64;
#pragma unroll
    for (int jd = 0; jd < 4; ++jd) {
      uint2 o;
      o.x = pk_bf16(accO[jd][0] * invl, accO[jd][1] * invl);
      o.y = pk_bf16(accO[jd][2] * invl, accO[jd][3] * invl);
      *reinterpret_cast<uint2*>(dst + jd * 16 + hg * 4) = o;
    }
  }
}

extern "C" void kernel_launch(void* const* d_in, const int* in_sizes, int n_in,
                              void* d_out, int out_size, void* d_ws, size_t ws_size,
                              hipStream_t stream) {
  const float* x = (const float*)d_in[0];
  const float* w_qkv = (const float*)d_in[1];
  const float* b_qkv = (const float*)d_in[2];
  const float* w_proj = (const float*)d_in[3];
  const float* b_proj = (const float*)d_in[4];
  float* out = (float*)d_out;
  char* ws = (char*)d_ws;
  unsigned short* x_bf = (unsigned short*)(ws);                   // [0, 8MB)
  unsigned short* ao_bf = (unsigned short*)(ws);                  // overlay, [0, 8MB)
  unsigned short* wq_bf = (unsigned short*)(ws + (8ull << 20));   // [8, 14MB)
  unsigned short* wp_bf = (unsigned short*)(ws + (14ull << 20));  // [14, 16MB)
  unsigned short* q_bf = (unsigned short*)(ws + (16ull << 20));   // [16, 24MB)
  unsigned short* k_bf = (unsigned short*)(ws + (24ull << 20));   // [24, 32MB)
  unsigned short* vt_bf = (unsigned short*)(ws + (32ull << 20));  // [32, 40MB)  V^T

  cvt3_kernel<<<2048, 256, 0, stream>>>(x, x_bf, 4096 * 1024 / 4,
                                        w_qkv, wq_bf, 3072 * 1024 / 4,
                                        w_proj, wp_bf, 1024 * 1024 / 4);
  gemm_qkv_kernel<<<dim3(24, 32), 256, 0, stream>>>(x_bf, wq_bf, b_qkv, q_bf, k_bf, vt_bf);
  attn_kernel<<<dim3(16, 32), 512, 0, stream>>>(q_bf, k_bf, vt_bf, ao_bf);
  gemm_proj_kernel<<<dim3(8, 32), 256, 0, stream>>>(ao_bf, wp_bf, b_proj, out);
}